// Round 3
// baseline (223.164 us; speedup 1.0000x reference)
//
#include <hip/hip_runtime.h>
#include <math.h>

#define BB   16
#define RR   4096
#define NC   80          // foreground classes
#define KK   300
#define DD   100
#define CCAP 512         // per-(image,class) candidate cap (expected ~118, sigma ~11)
#define CAP  16384       // per-image kept-candidate cap (expected ~8800)
#define LCAP 48          // per-(block,class) local cap in kernel A
#define NBLK 16          // kernel-A blocks per image (4096 rows / 256)
#define NW   5           // 5*64 = 320 >= KK bitmask words
#define PAD  (NW * 64)   // 320 padded rank slots
#define HBINS 1280       // score histogram bins (used: 1128)
#define HPT   5          // bins per scan-thread (1280/256)
#define BIN0  0x7A99u    // (0x3D4CCCCD >> 15): bin of score==0.05f
#define ZCNT  20512      // ints to zero in A: g_cnt(16)+pad(16)+g_hist(20480)

typedef unsigned long long ull;

__device__ __forceinline__ float4 decode_box(const float4 pr, const float4 rg) {
    float dx = rg.x / 10.0f;
    float dy = rg.y / 10.0f;
    float dw = fminf(rg.z / 5.0f, 4.135166556742356f);
    float dh = fminf(rg.w / 5.0f, 4.135166556742356f);
    float w  = pr.z - pr.x + 1.0f;
    float h  = pr.w - pr.y + 1.0f;
    float cx = pr.x + 0.5f * w;
    float cy = pr.y + 0.5f * h;
    float pcx = dx * w + cx;
    float pcy = dy * h + cy;
    float pw  = expf(dw) * w;
    float ph  = expf(dh) * h;
    float x1 = pcx - 0.5f * pw;
    float y1 = pcy - 0.5f * ph;
    float x2 = pcx + 0.5f * pw - 1.0f;
    float y2 = pcy + 0.5f * ph - 1.0f;
    x1 = fminf(fmaxf(x1, 0.0f), 1332.0f);
    y1 = fminf(fmaxf(y1, 0.0f), 799.0f);
    x2 = fminf(fmaxf(x2, 0.0f), 1332.0f);
    y2 = fminf(fmaxf(y2, 0.0f), 799.0f);
    return make_float4(x1, y1, x2, y2);
}

// ---- Kernel A: direct-load softmax + per-(block,class) segment emit ----
// (unchanged from round 2 — will be measured via next round's top-5)
__global__ __launch_bounds__(256) void softmax_cand_kernel(
        const float* __restrict__ logits,
        ull*         __restrict__ cand2,     // [BB*NC][NBLK][LCAP]
        int*         __restrict__ cnt_blk,   // [BB*NC][NBLK]
        int*         __restrict__ zeros) {   // ws head: ZCNT ints to clear
    __shared__ ull   lbuf[NC * LCAP];
    __shared__ int   lhist[NC];

    const int tid  = threadIdx.x;
    const int row0 = blockIdx.x * 256;
    const int b    = blockIdx.x >> 4;
    const int blk  = blockIdx.x & 15;

    if (row0 + tid < ZCNT) zeros[row0 + tid] = 0;

    if (tid < NC) lhist[tid] = 0;
    __syncthreads();

    const float* rp = logits + (size_t)(row0 + tid) * 81;
    float v[81];
    #pragma unroll
    for (int q = 0; q < 20; ++q) {
        float4 t = *(const float4*)(rp + 4 * q);
        v[4 * q + 0] = t.x; v[4 * q + 1] = t.y;
        v[4 * q + 2] = t.z; v[4 * q + 3] = t.w;
    }
    v[80] = rp[80];

    float m = -1e30f;
    #pragma unroll
    for (int c = 0; c < 81; ++c) m = fmaxf(m, v[c]);

    float s = 0.0f;
    #pragma unroll
    for (int c = 0; c < 81; ++c) { float e = expf(v[c] - m); v[c] = e; s += e; }

    const unsigned rlow = (unsigned)((row0 + tid) & 4095);
    #pragma unroll
    for (int c = 1; c < 81; ++c) {
        float p = v[c] / s;
        if (p > 0.05f) {
            int ci  = c - 1;
            int pos = atomicAdd(&lhist[ci], 1);
            if (pos < LCAP)
                lbuf[ci * LCAP + pos] =
                    ((ull)__float_as_uint(p) << 32) | (unsigned)(~rlow);
        }
    }
    __syncthreads();

    if (tid < NC) {
        int h = lhist[tid]; if (h > LCAP) h = LCAP;
        cnt_blk[(b * NC + tid) * NBLK + blk] = h;
    }
    for (int idx = tid; idx < NC * LCAP; idx += 256) {
        int ci = idx / LCAP, j = idx - ci * LCAP;
        int h  = lhist[ci]; if (h > LCAP) h = LCAP;
        if (j < h)
            cand2[((size_t)(b * NC + ci) * NBLK + blk) * LCAP + j] = lbuf[idx];
    }
}

// ---- Kernel B: ONE WAVE per (image,class): compact + sort + decode + NMS + append ----
// 64-thread blocks: every __syncthreads degenerates to a waitcnt (no s_barrier
// partner waves), the 28 bitonic phases lose their barrier cost, no lane idles.
__global__ __launch_bounds__(64) void percls_kernel(
        const ull*   __restrict__ cand2,
        const int*   __restrict__ cnt_blk,
        const float* __restrict__ box_reg,
        const float* __restrict__ proposals,
        ull*         __restrict__ img_keys,  // [BB][CAP]
        unsigned*    __restrict__ img_meta,  // [BB][CAP]  (ci<<12 | r)
        int*         __restrict__ g_cnt,     // [BB]
        int*         __restrict__ g_hist) {  // [BB][HBINS]
    #pragma clang fp contract(off)
    __shared__ ull   keys[CCAP];                       // 4 KB (sorted keys)
    __shared__ float bx1[PAD], by1[PAD], bx2[PAD], by2[PAD], bar[PAD];  // 6.4 KB
    __shared__ int   sbase[NBLK + 1];

    const int bid  = blockIdx.x;     // 0..1279
    const int b    = bid / NC;
    const int ci   = bid % NC;
    const int lane = threadIdx.x;    // 0..63

    // parallel prefix of the 16 per-A-block counts (was: 16 serial loads on tid 0)
    {
        int cnt = (lane < NBLK) ? cnt_blk[bid * NBLK + lane] : 0;
        int sc  = cnt;
        #pragma unroll
        for (int d = 1; d < NBLK; d <<= 1) {
            int o = __shfl_up(sc, d, NBLK);
            if ((lane & (NBLK - 1)) >= d) sc += o;
        }
        if (lane < NBLK) sbase[lane + 1] = sc;
        if (lane == 0)   sbase[0] = 0;
    }
    __syncthreads();

    int M = sbase[NBLK]; if (M > CCAP) M = CCAP;
    int sortN = 2; while (sortN < M) sortN <<= 1;

    for (int i = lane; i < sortN; i += 64) keys[i] = 0ULL;
    __syncthreads();
    for (int s = 0; s < NBLK; ++s) {
        int lo = sbase[s], c = sbase[s + 1] - lo;
        const ull* srcp = cand2 + ((size_t)bid * NBLK + s) * LCAP;
        for (int i = lane; i < c; i += 64)
            if (lo + i < CCAP) keys[lo + i] = srcp[i];
    }
    __syncthreads();

    // adaptive bitonic sort, descending (identical key order; barrier-free wave sync)
    for (int kk = 2; kk <= sortN; kk <<= 1) {
        for (int j = kk >> 1; j > 0; j >>= 1) {
            for (int i = lane; i < sortN; i += 64) {
                int ixj = i ^ j;
                if (ixj > i) {
                    bool desc = ((i & kk) == 0);
                    ull a = keys[i], c = keys[ixj];
                    if (desc ? (a < c) : (a > c)) { keys[i] = c; keys[ixj] = a; }
                }
            }
            __syncthreads();
        }
    }

    const int N = (M < KK) ? M : KK;

    // gather+decode of ranks [0,N)
    for (int k2 = lane; k2 < N; k2 += 64) {
        unsigned r = ~(unsigned)(keys[k2] & 0xFFFFFFFFu);
        size_t n = (size_t)b * RR + r;
        const float4 pr = *(const float4*)(proposals + n * 4);
        const float4 rg = *(const float4*)(box_reg + n * 324 + (size_t)(ci + 1) * 4);
        float4 bb = decode_box(pr, rg);
        bx1[k2] = bb.x; by1[k2] = bb.y; bx2[k2] = bb.z; by2[k2] = bb.w;
        bar[k2] = (bb.z - bb.x + 1.0f) * (bb.w - bb.y + 1.0f);
    }
    __syncthreads();

    // ---- NMS + append (whole block = the wave) ----
    {
        ull keepw[NW];
        #pragma unroll
        for (int w = 0; w < NW; ++w) {
            int lo = w * 64;
            keepw[w] = (N >= lo + 64) ? ~0ULL : (N <= lo ? 0ULL : ((1ULL << (N - lo)) - 1ULL));
        }

        #pragma unroll
        for (int t = 0; t < NW; ++t) {
            if (t * 64 >= N) break;
            const int i = t * 64 + lane;
            const float ax1 = bx1[i], ay1 = by1[i],
                        ax2 = bx2[i], ay2 = by2[i], aar = bar[i];
            ull sup[NW];
            #pragma unroll
            for (int w = 0; w < NW; ++w) {
                ull mword = 0ULL;
                if (w >= t && w * 64 < N) {
                    int jlo = w * 64; if (jlo < i + 1) jlo = i + 1;
                    int jhi = w * 64 + 64; if (jhi > N) jhi = N;
                    for (int j = jlo; j < jhi; ++j) {
                        float ltx = fmaxf(ax1, bx1[j]);
                        float lty = fmaxf(ay1, by1[j]);
                        float rbx = fminf(ax2, bx2[j]);
                        float rby = fminf(ay2, by2[j]);
                        float iw  = fmaxf(rbx - ltx + 1.0f, 0.0f);
                        float ih  = fmaxf(rby - lty + 1.0f, 0.0f);
                        float inter = iw * ih;
                        float iou   = inter / ((aar + bar[j]) - inter);
                        if (iou > 0.5f) mword |= 1ULL << (j - w * 64);
                    }
                }
                sup[w] = mword;
            }
            ull rowany = 0ULL;
            #pragma unroll
            for (int w = 0; w < NW; ++w) rowany |= sup[w];
            const ull act = __ballot(rowany != 0ULL);

            ull mloop = keepw[t] & act;
            while (mloop) {
                int l = __builtin_ctzll(mloop);
                if ((keepw[t] >> l) & 1ULL) {
                    #pragma unroll
                    for (int w = 0; w < NW; ++w) {
                        if (w >= t && w * 64 < N)
                            keepw[w] &= ~__shfl(sup[w], l);
                    }
                }
                ull below = (l >= 63) ? ~0ULL : ((1ULL << (l + 1)) - 1ULL);
                mloop = keepw[t] & act & ~below;
            }
        }

        int total = 0;
        #pragma unroll
        for (int w = 0; w < NW; ++w) total += __popcll(keepw[w]);
        int base0 = 0;
        if (lane == 0) base0 = atomicAdd(&g_cnt[b], total);
        base0 = __shfl(base0, 0);

        int acc = 0;
        #pragma unroll
        for (int w = 0; w < NW; ++w) {
            if (w * 64 < N) {
                const ull km = keepw[w];
                const int k2 = w * 64 + lane;
                if ((km >> lane) & 1ULL) {
                    int rank = __popcll(km & ((1ULL << lane) - 1ULL));
                    int pos  = base0 + acc + rank;
                    if (pos < CAP) {
                        ull key = keys[k2];
                        unsigned sb = (unsigned)(key >> 32);
                        unsigned r  = ~(unsigned)(key & 0xFFFFFFFFu);
                        unsigned fi = (unsigned)(ci * KK + k2);
                        img_keys[(size_t)b * CAP + pos] =
                            ((ull)sb << 32) | (unsigned)(~fi);
                        img_meta[(size_t)b * CAP + pos] = ((unsigned)ci << 12) | (r & 4095u);
                        int bin = (int)((sb >> 15) - BIN0);
                        bin = (bin < 0) ? 0 : (bin >= HBINS ? HBINS - 1 : bin);
                        atomicAdd(&g_hist[b * HBINS + bin], 1);
                    }
                }
                acc += __popcll(km);
            }
        }
    }
}

// ---- Kernel C: threshold from prebuilt hist + gather + wave sort + emit ----
__global__ __launch_bounds__(1024) void topd_kernel(
        const ull*      __restrict__ img_keys,
        const unsigned* __restrict__ img_meta,
        const int*      __restrict__ g_cnt,
        const int*      __restrict__ g_hist,
        const float*    __restrict__ box_reg,
        const float*    __restrict__ proposals,
        float*          __restrict__ out) {
    __shared__ int  suf[256];
    __shared__ ull  pk[256];
    __shared__ int  ps[256];
    __shared__ int  sh_cnt, sh_tb;

    const int b   = blockIdx.x;
    const int tid = threadIdx.x;
    int M = g_cnt[b]; if (M > CAP) M = CAP;
    const ull* kp = img_keys + (size_t)b * CAP;
    const int* hh = g_hist + b * HBINS;

    if (tid == 0) { sh_cnt = 0; sh_tb = 0; }
    __syncthreads();

    int h[HPT], tot = 0;
    if (tid < 256) {
        #pragma unroll
        for (int r = 0; r < HPT; ++r) { h[r] = hh[tid * HPT + r]; tot += h[r]; }
        suf[tid] = tot;
    }
    __syncthreads();
    for (int off = 1; off < 256; off <<= 1) {
        int add = 0;
        if (tid < 256 && tid + off < 256) add = suf[tid + off];
        __syncthreads();
        if (tid < 256) suf[tid] += add;
        __syncthreads();
    }
    if (tid < 256) {
        int cum = suf[tid] - tot;
        #pragma unroll
        for (int jj = HPT - 1; jj >= 0; --jj) {
            int prev = cum;
            cum += h[jj];
            if (cum >= DD && prev < DD) sh_tb = tid * HPT + jj;
        }
    }
    __syncthreads();
    const unsigned keyLo = ((unsigned)sh_tb + BIN0) << 15;

    for (int i = tid; i < M; i += 1024) {
        ull key = kp[i];
        if ((unsigned)(key >> 32) >= keyLo) {
            int p = atomicAdd(&sh_cnt, 1);
            if (p < 256) { pk[p] = key; ps[p] = i; }
        }
    }
    __syncthreads();

    if (tid < 64) {
        const int lane  = tid;
        int ngath = sh_cnt; if (ngath > 256) ngath = 256;

        ull k4[4]; int s4[4];
        #pragma unroll
        for (int q = 0; q < 4; ++q) {
            int i = lane + 64 * q;
            bool vld = (i < ngath);
            k4[q] = vld ? pk[i] : 0ULL;
            s4[q] = vld ? ps[i] : -1;
        }

        #pragma unroll
        for (int k = 2; k <= 256; k <<= 1) {
            #pragma unroll
            for (int j = k >> 1; j > 0; j >>= 1) {
                if (j >= 64) {
                    const int qj = j >> 6;
                    #pragma unroll
                    for (int q = 0; q < 4; ++q) {
                        if ((q & qj) == 0 && (q + qj) < 4) {
                            int i0 = lane + 64 * q;
                            bool desc = ((i0 & k) == 0);
                            ull x = k4[q], y = k4[q + qj];
                            bool sw = desc ? (x < y) : (x > y);
                            if (sw) {
                                k4[q] = y; k4[q + qj] = x;
                                int t = s4[q]; s4[q] = s4[q + qj]; s4[q + qj] = t;
                            }
                        }
                    }
                } else {
                    #pragma unroll
                    for (int q = 0; q < 4; ++q) {
                        int i0 = lane + 64 * q;
                        bool desc  = ((i0 & k) == 0);
                        bool lower = ((lane & j) == 0);
                        ull pv = __shfl_xor(k4[q], j);
                        int sv = __shfl_xor(s4[q], j);
                        bool take = (desc == lower) ? (pv > k4[q]) : (pv < k4[q]);
                        if (take) { k4[q] = pv; s4[q] = sv; }
                    }
                }
            }
        }

        #pragma unroll
        for (int q = 0; q < 2; ++q) {
            int p = lane + 64 * q;
            if (p < DD) {
                float s; float4 bb; int label;
                if (p < ngath) {
                    ull key = k4[q];
                    unsigned fi   = ~(unsigned)(key & 0xFFFFFFFFu);
                    unsigned meta = img_meta[(size_t)b * CAP + s4[q]];
                    unsigned rr   = meta & 4095u;
                    unsigned ci   = meta >> 12;
                    s  = __uint_as_float((unsigned)(key >> 32));
                    size_t n = (size_t)b * RR + rr;
                    const float4 pr = *(const float4*)(proposals + n * 4);
                    const float4 rg = *(const float4*)(box_reg + n * 324 + (size_t)(ci + 1) * 4);
                    bb = decode_box(pr, rg);
                    label = (int)(fi / KK) + 1;
                } else {
                    s = -1.0f; bb = make_float4(0.0f, 0.0f, 0.0f, 0.0f); label = 0;
                }
                *(float4*)(out + (size_t)(b * DD + p) * 4) = bb;
                out[(size_t)BB * DD * 4 + b * DD + p] = s;
                out[(size_t)BB * DD * 4 + BB * DD + b * DD + p] = (float)label;
            }
        }
    }
}

extern "C" void kernel_launch(void* const* d_in, const int* in_sizes, int n_in,
                              void* d_out, int out_size, void* d_ws, size_t ws_size,
                              hipStream_t stream) {
    const float* logits    = (const float*)d_in[0];   // [B*R, 81]
    const float* box_reg   = (const float*)d_in[1];   // [B*R, 324]
    const float* proposals = (const float*)d_in[2];   // [B*R, 4]
    float* out = (float*)d_out;

    char* ws = (char*)d_ws;
    int*      g_cnt    = (int*)ws;                    //        64 B
    //        (ws + 64): 64 B reserved (zeroed, unused)
    int*      g_hist   = (int*)(ws + 128);            //    81,920 B  (first ZCNT ints zeroed by kernel A)
    int*      cnt_blk  = (int*)(ws + 82048);          //    81,920 B  (fully overwritten by A)
    ull*      cand2    = (ull*)(ws + 163968);         // 7,864,320 B  (ends 8,028,288)
    ull*      img_keys = (ull*)(ws + 8028288);        // 2,097,152 B  (ends 10,125,440)
    unsigned* img_meta = (unsigned*)(ws + 10125440);  // 1,048,576 B  (ends 11,174,016)

    softmax_cand_kernel<<<(BB * RR) / 256, 256, 0, stream>>>(logits, cand2, cnt_blk, (int*)ws);
    percls_kernel<<<BB * NC, 64, 0, stream>>>(cand2, cnt_blk, box_reg, proposals,
                                              img_keys, img_meta, g_cnt, g_hist);
    topd_kernel<<<BB, 1024, 0, stream>>>(img_keys, img_meta, g_cnt, g_hist,
                                         box_reg, proposals, out);
}

// Round 4
// 201.458 us; speedup vs baseline: 1.1077x; 1.1077x over previous
//
#include <hip/hip_runtime.h>
#include <math.h>

#define BB   16
#define RR   4096
#define NC   80          // foreground classes
#define KK   300
#define DD   100
#define CCAP 512         // per-(image,class) candidate cap (expected ~118, sigma ~11)
#define CAP  16384       // per-image kept-candidate cap (expected ~8800)
#define LCAP 48          // per-(block,class) local cap in kernel A
#define NBLK 16          // kernel-A blocks per image (4096 rows / 256)
#define NW   5           // 5*64 = 320 >= KK bitmask words
#define PAD  (NW * 64)   // 320 padded rank slots
#define HBINS 1280       // score histogram bins (used: 1128)
#define HPT   5          // bins per scan-thread (1280/256)
#define BIN0  0x7A99u    // (0x3D4CCCCD >> 15): bin of score==0.05f
#define ZCNT  20512      // ints to zero in A: g_cnt(16)+pad(16)+g_hist(20480)

typedef unsigned long long ull;

__device__ __forceinline__ float4 decode_box(const float4 pr, const float4 rg) {
    float dx = rg.x / 10.0f;
    float dy = rg.y / 10.0f;
    float dw = fminf(rg.z / 5.0f, 4.135166556742356f);
    float dh = fminf(rg.w / 5.0f, 4.135166556742356f);
    float w  = pr.z - pr.x + 1.0f;
    float h  = pr.w - pr.y + 1.0f;
    float cx = pr.x + 0.5f * w;
    float cy = pr.y + 0.5f * h;
    float pcx = dx * w + cx;
    float pcy = dy * h + cy;
    float pw  = expf(dw) * w;
    float ph  = expf(dh) * h;
    float x1 = pcx - 0.5f * pw;
    float y1 = pcy - 0.5f * ph;
    float x2 = pcx + 0.5f * pw - 1.0f;
    float y2 = pcy + 0.5f * ph - 1.0f;
    x1 = fminf(fmaxf(x1, 0.0f), 1332.0f);
    y1 = fminf(fmaxf(y1, 0.0f), 799.0f);
    x2 = fminf(fmaxf(x2, 0.0f), 1332.0f);
    y2 = fminf(fmaxf(y2, 0.0f), 799.0f);
    return make_float4(x1, y1, x2, y2);
}

// ---- Kernel A: direct-load softmax + per-(block,class) segment emit (unchanged) ----
__global__ __launch_bounds__(256) void softmax_cand_kernel(
        const float* __restrict__ logits,
        ull*         __restrict__ cand2,     // [BB*NC][NBLK][LCAP]
        int*         __restrict__ cnt_blk,   // [BB*NC][NBLK]
        int*         __restrict__ zeros) {   // ws head: ZCNT ints to clear
    __shared__ ull   lbuf[NC * LCAP];
    __shared__ int   lhist[NC];

    const int tid  = threadIdx.x;
    const int row0 = blockIdx.x * 256;
    const int b    = blockIdx.x >> 4;
    const int blk  = blockIdx.x & 15;

    if (row0 + tid < ZCNT) zeros[row0 + tid] = 0;

    if (tid < NC) lhist[tid] = 0;
    __syncthreads();

    const float* rp = logits + (size_t)(row0 + tid) * 81;
    float v[81];
    #pragma unroll
    for (int q = 0; q < 20; ++q) {
        float4 t = *(const float4*)(rp + 4 * q);
        v[4 * q + 0] = t.x; v[4 * q + 1] = t.y;
        v[4 * q + 2] = t.z; v[4 * q + 3] = t.w;
    }
    v[80] = rp[80];

    float m = -1e30f;
    #pragma unroll
    for (int c = 0; c < 81; ++c) m = fmaxf(m, v[c]);

    float s = 0.0f;
    #pragma unroll
    for (int c = 0; c < 81; ++c) { float e = expf(v[c] - m); v[c] = e; s += e; }

    const unsigned rlow = (unsigned)((row0 + tid) & 4095);
    #pragma unroll
    for (int c = 1; c < 81; ++c) {
        float p = v[c] / s;
        if (p > 0.05f) {
            int ci  = c - 1;
            int pos = atomicAdd(&lhist[ci], 1);
            if (pos < LCAP)
                lbuf[ci * LCAP + pos] =
                    ((ull)__float_as_uint(p) << 32) | (unsigned)(~rlow);
        }
    }
    __syncthreads();

    if (tid < NC) {
        int h = lhist[tid]; if (h > LCAP) h = LCAP;
        cnt_blk[(b * NC + tid) * NBLK + blk] = h;
    }
    for (int idx = tid; idx < NC * LCAP; idx += 256) {
        int ci = idx / LCAP, j = idx - ci * LCAP;
        int h  = lhist[ci]; if (h > LCAP) h = LCAP;
        if (j < h)
            cand2[((size_t)(b * NC + ci) * NBLK + blk) * LCAP + j] = lbuf[idx];
    }
}

// ---- Kernel B: per (image,class): rank-by-count sort fused with decode ----
// Unique keys => rank_i = #{j: key_j > key_i} is the exact descending sort.
// Replaces 28 barriered bitonic phases + separate gather with:
//   load keys -> barrier -> rank+decode+scatter -> barrier -> NMS.
// 256 threads (20 waves/CU at 5 blocks/CU) for latency hiding.
__global__ __launch_bounds__(256) void percls_kernel(
        const ull*   __restrict__ cand2,
        const int*   __restrict__ cnt_blk,
        const float* __restrict__ box_reg,
        const float* __restrict__ proposals,
        ull*         __restrict__ img_keys,  // [BB][CAP]
        unsigned*    __restrict__ img_meta,  // [BB][CAP]  (ci<<12 | r)
        int*         __restrict__ g_cnt,     // [BB]
        int*         __restrict__ g_hist) {  // [BB][HBINS]
    #pragma clang fp contract(off)
    __shared__ ull   keys[CCAP];                       // 4 KB   unsorted keys
    __shared__ ull   skey[PAD];                        // 2.56 KB rank-ordered keys
    __shared__ float bx1[PAD], by1[PAD], bx2[PAD], by2[PAD], bar[PAD];  // 6.4 KB
    __shared__ int   sbase[NBLK + 1];

    const int bid = blockIdx.x;     // 0..1279
    const int b   = bid / NC;
    const int ci  = bid % NC;
    const int tid = threadIdx.x;

    // wave-0 parallel prefix of the 16 per-A-block counts
    if (tid < 64) {
        int cnt = (tid < NBLK) ? cnt_blk[bid * NBLK + tid] : 0;
        int sc  = cnt;
        #pragma unroll
        for (int d = 1; d < NBLK; d <<= 1) {
            int o = __shfl_up(sc, d, NBLK);
            if ((tid & (NBLK - 1)) >= d) sc += o;
        }
        if (tid < NBLK) sbase[tid + 1] = sc;
        if (tid == 0)   sbase[0] = 0;
    }
    __syncthreads();

    int M = sbase[NBLK]; if (M > CCAP) M = CCAP;

    // flattened parallel segment compaction (all loads independent -> MLP)
    for (int idx = tid; idx < NBLK * LCAP; idx += 256) {
        int seg = idx / LCAP, j = idx - seg * LCAP;
        int lo  = sbase[seg], c = sbase[seg + 1] - lo;
        if (j < c) {
            int slot = lo + j;
            if (slot < CCAP)
                keys[slot] = cand2[((size_t)bid * NBLK + seg) * LCAP + j];
        }
    }
    __syncthreads();

    const int N = (M < KK) ? M : KK;

    // rank-by-count + decode + scatter: one thread per candidate
    for (int i = tid; i < M; i += 256) {
        ull ki = keys[i];
        int rank = 0;
        for (int j = 0; j < M; ++j) rank += (keys[j] > ki);  // broadcast LDS reads
        if (rank < PAD) {
            skey[rank] = ki;
            unsigned r = ~(unsigned)(ki & 0xFFFFFFFFu);
            size_t n = (size_t)b * RR + r;
            const float4 pr = *(const float4*)(proposals + n * 4);
            const float4 rg = *(const float4*)(box_reg + n * 324 + (size_t)(ci + 1) * 4);
            float4 bb = decode_box(pr, rg);
            bx1[rank] = bb.x; by1[rank] = bb.y; bx2[rank] = bb.z; by2[rank] = bb.w;
            bar[rank] = (bb.z - bb.x + 1.0f) * (bb.w - bb.y + 1.0f);
        }
    }
    __syncthreads();

    // ---- NMS + append: wave 0 (proven bit-path, LDS-sourced) ----
    if (tid < 64) {
        const int lane = tid;

        ull keepw[NW];
        #pragma unroll
        for (int w = 0; w < NW; ++w) {
            int lo = w * 64;
            keepw[w] = (N >= lo + 64) ? ~0ULL : (N <= lo ? 0ULL : ((1ULL << (N - lo)) - 1ULL));
        }

        #pragma unroll
        for (int t = 0; t < NW; ++t) {
            if (t * 64 >= N) break;
            const int i = t * 64 + lane;
            const float ax1 = bx1[i], ay1 = by1[i],
                        ax2 = bx2[i], ay2 = by2[i], aar = bar[i];
            ull sup[NW];
            #pragma unroll
            for (int w = 0; w < NW; ++w) {
                ull mword = 0ULL;
                if (w >= t && w * 64 < N) {
                    int jlo = w * 64; if (jlo < i + 1) jlo = i + 1;
                    int jhi = w * 64 + 64; if (jhi > N) jhi = N;
                    for (int j = jlo; j < jhi; ++j) {
                        float ltx = fmaxf(ax1, bx1[j]);
                        float lty = fmaxf(ay1, by1[j]);
                        float rbx = fminf(ax2, bx2[j]);
                        float rby = fminf(ay2, by2[j]);
                        float iw  = fmaxf(rbx - ltx + 1.0f, 0.0f);
                        float ih  = fmaxf(rby - lty + 1.0f, 0.0f);
                        float inter = iw * ih;
                        float iou   = inter / ((aar + bar[j]) - inter);
                        if (iou > 0.5f) mword |= 1ULL << (j - w * 64);
                    }
                }
                sup[w] = mword;
            }
            ull rowany = 0ULL;
            #pragma unroll
            for (int w = 0; w < NW; ++w) rowany |= sup[w];
            const ull act = __ballot(rowany != 0ULL);

            ull mloop = keepw[t] & act;
            while (mloop) {
                int l = __builtin_ctzll(mloop);
                if ((keepw[t] >> l) & 1ULL) {
                    #pragma unroll
                    for (int w = 0; w < NW; ++w) {
                        if (w >= t && w * 64 < N)
                            keepw[w] &= ~__shfl(sup[w], l);
                    }
                }
                ull below = (l >= 63) ? ~0ULL : ((1ULL << (l + 1)) - 1ULL);
                mloop = keepw[t] & act & ~below;
            }
        }

        int total = 0;
        #pragma unroll
        for (int w = 0; w < NW; ++w) total += __popcll(keepw[w]);
        int base0 = 0;
        if (lane == 0) base0 = atomicAdd(&g_cnt[b], total);
        base0 = __shfl(base0, 0);

        int acc = 0;
        #pragma unroll
        for (int w = 0; w < NW; ++w) {
            if (w * 64 < N) {
                const ull km = keepw[w];
                const int k2 = w * 64 + lane;
                if ((km >> lane) & 1ULL) {
                    int rank = __popcll(km & ((1ULL << lane) - 1ULL));
                    int pos  = base0 + acc + rank;
                    if (pos < CAP) {
                        ull key = skey[k2];
                        unsigned sb = (unsigned)(key >> 32);
                        unsigned r  = ~(unsigned)(key & 0xFFFFFFFFu);
                        unsigned fi = (unsigned)(ci * KK + k2);
                        img_keys[(size_t)b * CAP + pos] =
                            ((ull)sb << 32) | (unsigned)(~fi);
                        img_meta[(size_t)b * CAP + pos] = ((unsigned)ci << 12) | (r & 4095u);
                        int bin = (int)((sb >> 15) - BIN0);
                        bin = (bin < 0) ? 0 : (bin >= HBINS ? HBINS - 1 : bin);
                        atomicAdd(&g_hist[b * HBINS + bin], 1);
                    }
                }
                acc += __popcll(km);
            }
        }
    }
}

// ---- Kernel C: threshold from prebuilt hist + gather + wave sort + emit (unchanged) ----
__global__ __launch_bounds__(1024) void topd_kernel(
        const ull*      __restrict__ img_keys,
        const unsigned* __restrict__ img_meta,
        const int*      __restrict__ g_cnt,
        const int*      __restrict__ g_hist,
        const float*    __restrict__ box_reg,
        const float*    __restrict__ proposals,
        float*          __restrict__ out) {
    __shared__ int  suf[256];
    __shared__ ull  pk[256];
    __shared__ int  ps[256];
    __shared__ int  sh_cnt, sh_tb;

    const int b   = blockIdx.x;
    const int tid = threadIdx.x;
    int M = g_cnt[b]; if (M > CAP) M = CAP;
    const ull* kp = img_keys + (size_t)b * CAP;
    const int* hh = g_hist + b * HBINS;

    if (tid == 0) { sh_cnt = 0; sh_tb = 0; }
    __syncthreads();

    int h[HPT], tot = 0;
    if (tid < 256) {
        #pragma unroll
        for (int r = 0; r < HPT; ++r) { h[r] = hh[tid * HPT + r]; tot += h[r]; }
        suf[tid] = tot;
    }
    __syncthreads();
    for (int off = 1; off < 256; off <<= 1) {
        int add = 0;
        if (tid < 256 && tid + off < 256) add = suf[tid + off];
        __syncthreads();
        if (tid < 256) suf[tid] += add;
        __syncthreads();
    }
    if (tid < 256) {
        int cum = suf[tid] - tot;
        #pragma unroll
        for (int jj = HPT - 1; jj >= 0; --jj) {
            int prev = cum;
            cum += h[jj];
            if (cum >= DD && prev < DD) sh_tb = tid * HPT + jj;
        }
    }
    __syncthreads();
    const unsigned keyLo = ((unsigned)sh_tb + BIN0) << 15;

    for (int i = tid; i < M; i += 1024) {
        ull key = kp[i];
        if ((unsigned)(key >> 32) >= keyLo) {
            int p = atomicAdd(&sh_cnt, 1);
            if (p < 256) { pk[p] = key; ps[p] = i; }
        }
    }
    __syncthreads();

    if (tid < 64) {
        const int lane  = tid;
        int ngath = sh_cnt; if (ngath > 256) ngath = 256;

        ull k4[4]; int s4[4];
        #pragma unroll
        for (int q = 0; q < 4; ++q) {
            int i = lane + 64 * q;
            bool vld = (i < ngath);
            k4[q] = vld ? pk[i] : 0ULL;
            s4[q] = vld ? ps[i] : -1;
        }

        #pragma unroll
        for (int k = 2; k <= 256; k <<= 1) {
            #pragma unroll
            for (int j = k >> 1; j > 0; j >>= 1) {
                if (j >= 64) {
                    const int qj = j >> 6;
                    #pragma unroll
                    for (int q = 0; q < 4; ++q) {
                        if ((q & qj) == 0 && (q + qj) < 4) {
                            int i0 = lane + 64 * q;
                            bool desc = ((i0 & k) == 0);
                            ull x = k4[q], y = k4[q + qj];
                            bool sw = desc ? (x < y) : (x > y);
                            if (sw) {
                                k4[q] = y; k4[q + qj] = x;
                                int t = s4[q]; s4[q] = s4[q + qj]; s4[q + qj] = t;
                            }
                        }
                    }
                } else {
                    #pragma unroll
                    for (int q = 0; q < 4; ++q) {
                        int i0 = lane + 64 * q;
                        bool desc  = ((i0 & k) == 0);
                        bool lower = ((lane & j) == 0);
                        ull pv = __shfl_xor(k4[q], j);
                        int sv = __shfl_xor(s4[q], j);
                        bool take = (desc == lower) ? (pv > k4[q]) : (pv < k4[q]);
                        if (take) { k4[q] = pv; s4[q] = sv; }
                    }
                }
            }
        }

        #pragma unroll
        for (int q = 0; q < 2; ++q) {
            int p = lane + 64 * q;
            if (p < DD) {
                float s; float4 bb; int label;
                if (p < ngath) {
                    ull key = k4[q];
                    unsigned fi   = ~(unsigned)(key & 0xFFFFFFFFu);
                    unsigned meta = img_meta[(size_t)b * CAP + s4[q]];
                    unsigned rr   = meta & 4095u;
                    unsigned ci   = meta >> 12;
                    s  = __uint_as_float((unsigned)(key >> 32));
                    size_t n = (size_t)b * RR + rr;
                    const float4 pr = *(const float4*)(proposals + n * 4);
                    const float4 rg = *(const float4*)(box_reg + n * 324 + (size_t)(ci + 1) * 4);
                    bb = decode_box(pr, rg);
                    label = (int)(fi / KK) + 1;
                } else {
                    s = -1.0f; bb = make_float4(0.0f, 0.0f, 0.0f, 0.0f); label = 0;
                }
                *(float4*)(out + (size_t)(b * DD + p) * 4) = bb;
                out[(size_t)BB * DD * 4 + b * DD + p] = s;
                out[(size_t)BB * DD * 4 + BB * DD + b * DD + p] = (float)label;
            }
        }
    }
}

extern "C" void kernel_launch(void* const* d_in, const int* in_sizes, int n_in,
                              void* d_out, int out_size, void* d_ws, size_t ws_size,
                              hipStream_t stream) {
    const float* logits    = (const float*)d_in[0];   // [B*R, 81]
    const float* box_reg   = (const float*)d_in[1];   // [B*R, 324]
    const float* proposals = (const float*)d_in[2];   // [B*R, 4]
    float* out = (float*)d_out;

    char* ws = (char*)d_ws;
    int*      g_cnt    = (int*)ws;                    //        64 B
    //        (ws + 64): 64 B reserved (zeroed, unused)
    int*      g_hist   = (int*)(ws + 128);            //    81,920 B  (first ZCNT ints zeroed by kernel A)
    int*      cnt_blk  = (int*)(ws + 82048);          //    81,920 B  (fully overwritten by A)
    ull*      cand2    = (ull*)(ws + 163968);         // 7,864,320 B  (ends 8,028,288)
    ull*      img_keys = (ull*)(ws + 8028288);        // 2,097,152 B  (ends 10,125,440)
    unsigned* img_meta = (unsigned*)(ws + 10125440);  // 1,048,576 B  (ends 11,174,016)

    softmax_cand_kernel<<<(BB * RR) / 256, 256, 0, stream>>>(logits, cand2, cnt_blk, (int*)ws);
    percls_kernel<<<BB * NC, 256, 0, stream>>>(cand2, cnt_blk, box_reg, proposals,
                                               img_keys, img_meta, g_cnt, g_hist);
    topd_kernel<<<BB, 1024, 0, stream>>>(img_keys, img_meta, g_cnt, g_hist,
                                         box_reg, proposals, out);
}